// Round 16
// baseline (690.464 us; speedup 1.0000x reference)
//
#include <hip/hip_runtime.h>
#include <cmath>

#define NB 8
#define NT 512
#define NC 2048
#define NH 32
#define NZ 64
static constexpr float GN_EPS = 1e-5f * 64.0f;

typedef _Float16 f16;
typedef __attribute__((ext_vector_type(8))) _Float16 f16x8;
typedef __attribute__((ext_vector_type(4))) _Float16 f16x4;
typedef __attribute__((ext_vector_type(4))) float f4;

static __device__ __forceinline__ void gload16(const void* gp, void* lp) {
  __builtin_amdgcn_global_load_lds(
      (const __attribute__((address_space(1))) void*)gp,
      (__attribute__((address_space(3))) void*)lp, 16, 0, 0);
}

// ---------------- transpose + cast fp32 [R,Cc] -> f16 [Cc,R] ----------------
__global__ void k_transpose_cast(const float* __restrict__ in, f16* __restrict__ out,
                                 int R, int Cc) {
  __shared__ float tile[32][33];
  int c0 = blockIdx.x * 32, r0 = blockIdx.y * 32;
  int tx = threadIdx.x, ty = threadIdx.y;
#pragma unroll
  for (int i = 0; i < 4; ++i)
    tile[ty + i * 8][tx] = in[(size_t)(r0 + ty + i * 8) * Cc + c0 + tx];
  __syncthreads();
#pragma unroll
  for (int i = 0; i < 4; ++i)
    out[(size_t)(c0 + ty + i * 8) * R + r0 + tx] = (f16)tile[tx][ty + i * 8];
}

// ------------- transpose + hi/lo split fp32 [R,Cc] -> f16 [Cc,R] x2 -------------
__global__ void k_transpose_split(const float* __restrict__ in, f16* __restrict__ ohi,
                                  f16* __restrict__ olo, int R, int Cc) {
  __shared__ float tile[32][33];
  int c0 = blockIdx.x * 32, r0 = blockIdx.y * 32;
  int tx = threadIdx.x, ty = threadIdx.y;
#pragma unroll
  for (int i = 0; i < 4; ++i)
    tile[ty + i * 8][tx] = in[(size_t)(r0 + ty + i * 8) * Cc + c0 + tx];
  __syncthreads();
#pragma unroll
  for (int i = 0; i < 4; ++i) {
    float v = tile[tx][ty + i * 8];
    f16 h = (f16)v;
    size_t o = (size_t)(c0 + ty + i * 8) * R + r0 + tx;
    ohi[o] = h;
    olo[o] = (f16)(v - (float)h);
  }
}

// ---- five maa_w2 transposes in one launch: z = feature, [32,2048] -> [2048,32] ----
__global__ void k_tsplit_w2(const float* __restrict__ in0, f16* __restrict__ ohi0,
                            f16* __restrict__ olo0) {
  __shared__ float tile[32][33];
  int f = blockIdx.z;
  const float* in = in0 + (size_t)f * 32 * 2048;
  f16* ohi = ohi0 + (size_t)f * 2048 * 32;
  f16* olo = olo0 + (size_t)f * 2048 * 32;
  int c0 = blockIdx.x * 32;
  int tx = threadIdx.x, ty = threadIdx.y;
#pragma unroll
  for (int i = 0; i < 4; ++i)
    tile[ty + i * 8][tx] = in[(size_t)(ty + i * 8) * 2048 + c0 + tx];
  __syncthreads();
#pragma unroll
  for (int i = 0; i < 4; ++i) {
    float v = tile[tx][ty + i * 8];
    f16 h = (f16)v;
    size_t o = (size_t)(c0 + ty + i * 8) * 32 + tx;
    ohi[o] = h;
    olo[o] = (f16)(v - (float)h);
  }
}

// -------- xxx = x + (shift - x) * maa_x  -> f16 hi/lo planes --------
__global__ void k_xxx(const float* __restrict__ hs, const float* __restrict__ shift_st,
                      const int* __restrict__ positions, const float* __restrict__ maa_x,
                      f16* __restrict__ xh, f16* __restrict__ xl) {
  int i = blockIdx.x * blockDim.x + threadIdx.x;
  int idx = i * 4;
  int c = idx & (NC - 1);
  int t = idx >> 11;
  int b = t >> 9;
  float er = (positions[b * NT] == 0) ? expf(-100.0f) : 1.0f;
  const float4 x = *(const float4*)(hs + idx);
  const float4 sh = *(const float4*)(shift_st + b * NC + c);
  const float4 mx = *(const float4*)(maa_x + c);
  float ov[4];
  ov[0] = x.x + (sh.x * er - x.x) * mx.x;
  ov[1] = x.y + (sh.y * er - x.y) * mx.y;
  ov[2] = x.z + (sh.z * er - x.z) * mx.z;
  ov[3] = x.w + (sh.w * er - x.w) * mx.w;
  f16x4 h4, l4;
#pragma unroll
  for (int j = 0; j < 4; ++j) {
    f16 h = (f16)ov[j];
    h4[j] = h;
    l4[j] = (f16)(ov[j] - (float)h);
  }
  *(f16x4*)(xh + idx) = h4;
  *(f16x4*)(xl + idx) = l4;
}

static __device__ __forceinline__ void split4(const float4 v, int base, f16x8& hi, f16x8& lo) {
  float x[4] = {v.x, v.y, v.z, v.w};
#pragma unroll
  for (int j = 0; j < 4; ++j) {
    f16 h = (f16)x[j];
    hi[base + j] = h;
    lo[base + j] = (f16)(x[j] - (float)h);
  }
}

// ---- mix1: mixb = tanh(xxx @ w1)  M=4096 N=160 K=2048, A hi/lo planes, fp32 out ----
__global__ __launch_bounds__(64) void k_mix1_split(const f16* __restrict__ Ah,
                                                   const f16* __restrict__ Al,
                                                   const f16* __restrict__ Bhi,
                                                   const f16* __restrict__ Blo,
                                                   float* __restrict__ out) {
  int m0 = blockIdx.x * 16, n0 = blockIdx.y * 16;
  int lane = threadIdx.x, lr = lane & 15, kq = lane >> 4;
  f4 acc = {0.f, 0.f, 0.f, 0.f};
  const f16* ah0 = Ah + (size_t)(m0 + lr) * 2048 + kq * 8;
  const f16* al0 = Al + (size_t)(m0 + lr) * 2048 + kq * 8;
  const f16* bh0 = Bhi + (size_t)(n0 + lr) * 2048 + kq * 8;
  const f16* bl0 = Blo + (size_t)(n0 + lr) * 2048 + kq * 8;
  for (int k0 = 0; k0 < 2048; k0 += 32) {
    f16x8 ah = *(const f16x8*)(ah0 + k0);
    f16x8 al = *(const f16x8*)(al0 + k0);
    f16x8 bh = *(const f16x8*)(bh0 + k0);
    f16x8 bl = *(const f16x8*)(bl0 + k0);
    acc = __builtin_amdgcn_mfma_f32_16x16x32_f16(ah, bh, acc, 0, 0, 0);
    acc = __builtin_amdgcn_mfma_f32_16x16x32_f16(ah, bl, acc, 0, 0, 0);
    acc = __builtin_amdgcn_mfma_f32_16x16x32_f16(al, bh, acc, 0, 0, 0);
  }
#pragma unroll
  for (int r = 0; r < 4; ++r)
    out[(size_t)(m0 + kq * 4 + r) * 160 + n0 + lr] = tanhf(acc[r]);
}

// ---- tmp5: mix2 (K=32 per feature, split) + fused 5-way mix epilogue ----
__global__ __launch_bounds__(64) void k_tmp5_split(const float* __restrict__ mixb,
    const f16* __restrict__ Bhi, const f16* __restrict__ Blo,
    const float* __restrict__ hs, const float* __restrict__ shift_st,
    const int* __restrict__ positions,
    const float* __restrict__ maa_w, const float* __restrict__ maa_k,
    const float* __restrict__ maa_v, const float* __restrict__ maa_r,
    const float* __restrict__ maa_g,
    f16* __restrict__ th, f16* __restrict__ tl, f16* __restrict__ kx,
    f16* __restrict__ vx, f16* __restrict__ rx, f16* __restrict__ gx) {
  int m0 = blockIdx.x * 16, n0 = blockIdx.y * 16;
  int lane = threadIdx.x, lr = lane & 15, kq = lane >> 4;
  f4 acc[5];
#pragma unroll
  for (int f = 0; f < 5; ++f) acc[f] = (f4){0.f, 0.f, 0.f, 0.f};
  const float* ap = mixb + (size_t)(m0 + lr) * 160 + kq * 8;
#pragma unroll
  for (int f = 0; f < 5; ++f) {
    f16x8 ah, al;
    split4(*(const float4*)(ap + f * 32), 0, ah, al);
    split4(*(const float4*)(ap + f * 32 + 4), 4, ah, al);
    size_t bi = ((size_t)f * 2048 + n0 + lr) * 32 + kq * 8;
    f16x8 bh = *(const f16x8*)(Bhi + bi);
    f16x8 bl = *(const f16x8*)(Blo + bi);
    acc[f] = __builtin_amdgcn_mfma_f32_16x16x32_f16(ah, bh, acc[f], 0, 0, 0);
    acc[f] = __builtin_amdgcn_mfma_f32_16x16x32_f16(ah, bl, acc[f], 0, 0, 0);
    acc[f] = __builtin_amdgcn_mfma_f32_16x16x32_f16(al, bh, acc[f], 0, 0, 0);
  }
  int c = n0 + lr;
  float mw = maa_w[c], mk = maa_k[c], mv = maa_v[c], mr = maa_r[c], mg = maa_g[c];
#pragma unroll
  for (int r = 0; r < 4; ++r) {
    int t = m0 + kq * 4 + r;
    int b = t >> 9;
    float er = (positions[b * NT] == 0) ? expf(-100.0f) : 1.0f;
    float x = hs[(size_t)t * NC + c];
    float xxv = shift_st[b * NC + c] * er - x;
    size_t oi = (size_t)t * NC + c;
    float tv = x + xxv * (mw + acc[0][r]);
    f16 hh = (f16)tv;
    th[oi] = hh;
    tl[oi] = (f16)(tv - (float)hh);
    kx[oi] = (f16)(x + xxv * (mk + acc[1][r]));
    vx[oi] = (f16)(x + xxv * (mv + acc[2][r]));
    rx[oi] = (f16)(x + xxv * (mr + acc[3][r]));
    gx[oi] = (f16)(x + xxv * (mg + acc[4][r]));
  }
}

// ---- wd1 = tanh(tdin @ dw1)  M=4096 N=64 K=2048, A hi/lo planes, out hi/lo ----
__global__ __launch_bounds__(64) void k_wd1_split(const f16* __restrict__ Ah,
                                                  const f16* __restrict__ Al,
                                                  const f16* __restrict__ Bhi,
                                                  const f16* __restrict__ Blo,
                                                  f16* __restrict__ wh,
                                                  f16* __restrict__ wl) {
  int m0 = blockIdx.x * 16, n0 = blockIdx.y * 16;
  int lane = threadIdx.x, lr = lane & 15, kq = lane >> 4;
  f4 acc = {0.f, 0.f, 0.f, 0.f};
  const f16* ah0 = Ah + (size_t)(m0 + lr) * 2048 + kq * 8;
  const f16* al0 = Al + (size_t)(m0 + lr) * 2048 + kq * 8;
  const f16* bh0 = Bhi + (size_t)(n0 + lr) * 2048 + kq * 8;
  const f16* bl0 = Blo + (size_t)(n0 + lr) * 2048 + kq * 8;
  for (int k0 = 0; k0 < 2048; k0 += 32) {
    f16x8 ah = *(const f16x8*)(ah0 + k0);
    f16x8 al = *(const f16x8*)(al0 + k0);
    f16x8 bh = *(const f16x8*)(bh0 + k0);
    f16x8 bl = *(const f16x8*)(bl0 + k0);
    acc = __builtin_amdgcn_mfma_f32_16x16x32_f16(ah, bh, acc, 0, 0, 0);
    acc = __builtin_amdgcn_mfma_f32_16x16x32_f16(ah, bl, acc, 0, 0, 0);
    acc = __builtin_amdgcn_mfma_f32_16x16x32_f16(al, bh, acc, 0, 0, 0);
  }
#pragma unroll
  for (int r = 0; r < 4; ++r) {
    float tv = tanhf(acc[r]);
    f16 hh = (f16)tv;
    size_t oi = (size_t)(m0 + kq * 4 + r) * 64 + n0 + lr;
    wh[oi] = hh;
    wl[oi] = (f16)(tv - (float)hh);
  }
}

// ---- ew = exp(-exp(time_decay + wd1 @ dw2))  (exp hoisted out of scan) ----
__global__ __launch_bounds__(64) void k_wdecay_split(const f16* __restrict__ Ah,
                                                     const f16* __restrict__ Al,
                                                     const f16* __restrict__ Bhi,
                                                     const f16* __restrict__ Blo,
                                                     const float* __restrict__ time_decay,
                                                     float* __restrict__ ewout) {
  int m0 = blockIdx.x * 16, n0 = blockIdx.y * 16;
  int lane = threadIdx.x, lr = lane & 15, kq = lane >> 4;
  f4 acc = {0.f, 0.f, 0.f, 0.f};
#pragma unroll
  for (int kk = 0; kk < 2; ++kk) {
    size_t ai = (size_t)(m0 + lr) * 64 + kk * 32 + kq * 8;
    f16x8 ah = *(const f16x8*)(Ah + ai);
    f16x8 al = *(const f16x8*)(Al + ai);
    size_t bi = (size_t)(n0 + lr) * 64 + kk * 32 + kq * 8;
    f16x8 bh = *(const f16x8*)(Bhi + bi);
    f16x8 bl = *(const f16x8*)(Blo + bi);
    acc = __builtin_amdgcn_mfma_f32_16x16x32_f16(ah, bh, acc, 0, 0, 0);
    acc = __builtin_amdgcn_mfma_f32_16x16x32_f16(ah, bl, acc, 0, 0, 0);
    acc = __builtin_amdgcn_mfma_f32_16x16x32_f16(al, bh, acc, 0, 0, 0);
  }
  int c = n0 + lr;
  float td = time_decay[c];
#pragma unroll
  for (int r = 0; r < 4; ++r) {
    int t = m0 + kq * 4 + r;
    ewout[(size_t)t * NC + c] = expf(-expf(td + acc[r]));
  }
}

// ---- f16 big GEMM 128x128x64: counted-vmcnt dbuf pipeline (T4) + XOR swizzle ----
#define GBM 128
#define GBN 128
#define GBK 64

template <int EPI>
__global__ __launch_bounds__(256) void k_gemm_big(const f16* __restrict__ A,
                                                  const f16* __restrict__ Bt,
                                                  float* __restrict__ Cf,
                                                  f16* __restrict__ Cb, int K) {
  __shared__ __align__(16) f16 As[2][GBM][GBK];
  __shared__ __align__(16) f16 Bs[2][GBN][GBK];
  int nwg = gridDim.x * gridDim.y;
  int wg = blockIdx.y * gridDim.x + blockIdx.x;
  int swz = (wg & 7) * (nwg >> 3) + (wg >> 3);
  int n0 = (swz % gridDim.x) * GBN;
  int m0 = (swz / gridDim.x) * GBM;
  int tid = threadIdx.x;
  int wid = tid >> 6, lane = tid & 63;
  int wr = wid >> 1, wc = wid & 1;
  int lr = lane & 15, kq = lane >> 4;
  int sw = lr & 7;
  int gunit = (lane & 7) ^ (lane >> 3);
  const f16* aL = A + (size_t)(m0 + wid * 32 + (lane >> 3)) * K + gunit * 8;
  const f16* bL = Bt + (size_t)(n0 + wid * 32 + (lane >> 3)) * K + gunit * 8;
  f4 acc[4][4];
#pragma unroll
  for (int m = 0; m < 4; ++m)
#pragma unroll
    for (int n = 0; n < 4; ++n) acc[m][n] = (f4){0.f, 0.f, 0.f, 0.f};

  auto stage = [&](int buf, int t) {
    int k0 = t * GBK;
#pragma unroll
    for (int i = 0; i < 4; ++i) {
      gload16(aL + k0 + (size_t)i * 8 * K, &As[buf][wid * 32 + i * 8][0]);
      gload16(bL + k0 + (size_t)i * 8 * K, &Bs[buf][wid * 32 + i * 8][0]);
    }
  };

  int niter = K / GBK;
  stage(0, 0);
  stage(1, 1);
  for (int it = 0; it < niter; ++it) {
    if (it == niter - 1)
      asm volatile("s_waitcnt vmcnt(0)" ::: "memory");
    else
      asm volatile("s_waitcnt vmcnt(8)" ::: "memory");
    __builtin_amdgcn_sched_barrier(0);
    __builtin_amdgcn_s_barrier();  // all waves' tile-it data resident
    int cur = it & 1;
#pragma unroll
    for (int kk = 0; kk < 2; ++kk) {
      f16x8 af[4], bfv[4];
      int un = ((kk * 4 + kq) ^ sw) * 8;
#pragma unroll
      for (int m = 0; m < 4; ++m)
        af[m] = *(const f16x8*)&As[cur][wr * 64 + m * 16 + lr][un];
#pragma unroll
      for (int n = 0; n < 4; ++n)
        bfv[n] = *(const f16x8*)&Bs[cur][wc * 64 + n * 16 + lr][un];
#pragma unroll
      for (int m = 0; m < 4; ++m)
#pragma unroll
        for (int n = 0; n < 4; ++n)
          acc[m][n] = __builtin_amdgcn_mfma_f32_16x16x32_f16(af[m], bfv[n], acc[m][n], 0, 0, 0);
    }
    __builtin_amdgcn_s_barrier();  // all reads of buf[cur] done
    if (it + 2 < niter) stage(cur, it + 2);
  }
#pragma unroll
  for (int m = 0; m < 4; ++m) {
    int row0 = m0 + wr * 64 + m * 16 + kq * 4;
#pragma unroll
    for (int n = 0; n < 4; ++n) {
      int col = n0 + wc * 64 + n * 16 + lr;
#pragma unroll
      for (int r = 0; r < 4; ++r) {
        float v = acc[m][n][r];
        size_t oi = (size_t)(row0 + r) * NC + col;
        if (EPI == 0) {
          Cf[oi] = v;
        } else {
          float s = v / (1.0f + expf(-v));
          Cb[oi] = (f16)s;
        }
      }
    }
  }
}

// ------------- chunked WKV scan: ONE WAVE per (b,h,chunk), L=64 -------------
// Single-wave block: NO barriers. Counted vmcnt keeps 2 groups in flight.
// ewb holds precomputed exp(w); reset folded into S-init scale.
// oacc reduced via 4 independent partials (breaks 64-deep FMA chain).
__global__ __launch_bounds__(64) void k_scanE(
    const float* rb, const float* __restrict__ kb,
    const float* __restrict__ vb, const float* __restrict__ ewb,
    const float* __restrict__ kvstate, const int* __restrict__ positions,
    const float* __restrict__ faaaa, f16* __restrict__ o,
    float* rtil, float* __restrict__ Ebuf, float* __restrict__ Dbuf) {
  int blk = blockIdx.x;
  int bh = blk >> 3, c = blk & 7;
  int b = bh >> 5, h = bh & 31;
  int zz = threadIdx.x;
  __shared__ __align__(16) float stg[2][4][4][64];  // [buf][r,k,ew,v][step][ch]
  float S[64];
  if (c == 0) {
    const float* S0 = kvstate + (size_t)bh * 4096;
    float sc = (positions[b * NT] == 0) ? expf(-100.0f) : 1.0f;
#pragma unroll
    for (int j = 0; j < 64; ++j) S[j] = S0[j * 64 + zz] * sc;
  } else {
#pragma unroll
    for (int j = 0; j < 64; ++j) S[j] = 0.f;
  }
  float u = faaaa[h * 64 + zz];
  const int row0 = b * NT + c * 64;
  const int lrow = zz >> 4, lcol = (zz & 15) * 4;

  auto stage = [&](int buf, int T) {
    size_t goff = (size_t)(row0 + T + lrow) * NC + h * 64 + lcol;
    gload16(rb + goff, &stg[buf][0][0][0]);
    gload16(kb + goff, &stg[buf][1][0][0]);
    gload16(ewb + goff, &stg[buf][2][0][0]);
    gload16(vb + goff, &stg[buf][3][0][0]);
  };
  stage(0, 0);
  stage(1, 4);
  float Pw = 1.0f;
  for (int g = 0; g < 16; ++g) {
    if (g == 15)
      asm volatile("s_waitcnt vmcnt(0)" ::: "memory");
    else
      asm volatile("s_waitcnt vmcnt(4)" ::: "memory");
    __builtin_amdgcn_sched_barrier(0);
    int cur = g & 1;
#pragma unroll
    for (int j = 0; j < 4; ++j) {
      int t = g * 4 + j;
      size_t rowoff = (size_t)(row0 + t) * NC + h * 64;
      float vr = stg[cur][0][j][zz];
      float vk = stg[cur][1][j][zz];
      float vew = stg[cur][2][j][zz];
      float vv = stg[cur][3][j][zz];
      float q = vr * u * vk;
      q += __shfl_xor(q, 1);  q += __shfl_xor(q, 2);  q += __shfl_xor(q, 4);
      q += __shfl_xor(q, 8);  q += __shfl_xor(q, 16); q += __shfl_xor(q, 32);
      if (c > 0) rtil[rowoff + zz] = vr * Pw;
      Pw *= vew;
      float oa0 = vv * q, oa1 = 0.f, oa2 = 0.f, oa3 = 0.f;
#pragma unroll
      for (int k0 = 0; k0 < 64; k0 += 16) {
#pragma unroll
        for (int kb4 = 0; kb4 < 16; kb4 += 4) {
          f4 r4 = *(const f4*)&stg[cur][0][j][k0 + kb4];
          f4 e4 = *(const f4*)&stg[cur][2][j][k0 + kb4];
          f4 k4 = *(const f4*)&stg[cur][1][j][k0 + kb4];
#pragma unroll
          for (int jj = 0; jj < 4; ++jj) {
            float sv = S[k0 + kb4 + jj];
            if (k0 == 0) oa0 = fmaf(r4[jj], sv, oa0);
            else if (k0 == 16) oa1 = fmaf(r4[jj], sv, oa1);
            else if (k0 == 32) oa2 = fmaf(r4[jj], sv, oa2);
            else oa3 = fmaf(r4[jj], sv, oa3);
            S[k0 + kb4 + jj] = fmaf(e4[jj], sv, k4[jj] * vv);
          }
        }
      }
      o[rowoff + zz] = (f16)((oa0 + oa1) + (oa2 + oa3));
    }
    if (g + 2 < 16) {
      asm volatile("s_waitcnt lgkmcnt(0)" ::: "memory");
      __builtin_amdgcn_sched_barrier(0);
      stage(cur, (g + 2) * 4);
    }
  }
  if (c < 7) {
    float* E = Ebuf + ((size_t)bh * 7 + c) * 4096;
#pragma unroll
    for (int j = 0; j < 64; ++j) E[j * 64 + zz] = S[j];
  }
  Dbuf[((size_t)bh * 8 + c) * 64 + zz] = Pw;
}

// ---- combine: slot(c-1) := true chunk-start state S_c,  c=1..7 (in-place walk) ----
__global__ __launch_bounds__(256) void k_comb(float* __restrict__ Ebuf,
                                              const float* __restrict__ Dbuf) {
  int bh = blockIdx.x, tid = threadIdx.x;
  int k = tid >> 2, v0 = (tid & 3) * 16;
  float* base = Ebuf + (size_t)bh * 7 * 4096;
  float S[16];
#pragma unroll
  for (int j = 0; j < 16; ++j) S[j] = base[k * 64 + v0 + j];
  for (int c = 2; c <= 7; ++c) {
    float d = Dbuf[((size_t)bh * 8 + (c - 1)) * 64 + k];
    float* slot = base + (size_t)(c - 1) * 4096;
#pragma unroll
    for (int j = 0; j < 16; ++j) {
      S[j] = fmaf(d, S[j], slot[k * 64 + v0 + j]);
      slot[k * 64 + v0 + j] = S[j];
    }
  }
}

// ---- fixup: o[c*64+t] += r~_t^T S_c  (block per (bh, c-1)), f16 RMW ----
__global__ __launch_bounds__(256) void k_fix(const float* __restrict__ rtil,
                                             const float* __restrict__ Ebuf,
                                             f16* __restrict__ o) {
  int blk = blockIdx.x;
  int bh = blk / 7, cm = blk - bh * 7;
  int c = cm + 1;
  int b = bh >> 5, h = bh & 31;
  __shared__ float Rs[64][65];
  __shared__ float Ss[64][65];
  int tid = threadIdx.x;
  const float* rsrc = rtil + ((size_t)(b * NT) + c * 64) * NC + h * NZ;
  const float* ssrc = Ebuf + ((size_t)bh * 7 + cm) * 4096;
#pragma unroll
  for (int q = 0; q < 4; ++q) {
    int li = tid * 4 + q;
    int rr = li >> 4, cc = (li & 15) * 4;
    float4 x = *(const float4*)(rsrc + (size_t)rr * NC + cc);
    Rs[rr][cc] = x.x; Rs[rr][cc + 1] = x.y; Rs[rr][cc + 2] = x.z; Rs[rr][cc + 3] = x.w;
    float4 y = *(const float4*)(ssrc + rr * 64 + cc);
    Ss[rr][cc] = y.x; Ss[rr][cc + 1] = y.y; Ss[rr][cc + 2] = y.z; Ss[rr][cc + 3] = y.w;
  }
  __syncthreads();
  int t = tid >> 2, v0 = (tid & 3) * 16;
  float acc[16];
#pragma unroll
  for (int j = 0; j < 16; ++j) acc[j] = 0.f;
  for (int k = 0; k < 64; ++k) {
    float rv = Rs[t][k];
#pragma unroll
    for (int j = 0; j < 16; ++j) acc[j] = fmaf(rv, Ss[k][v0 + j], acc[j]);
  }
  f16* op = o + ((size_t)(b * NT) + c * 64 + t) * NC + h * NZ + v0;
  f16x8 o0 = *(f16x8*)op, o1 = *(f16x8*)(op + 8);
#pragma unroll
  for (int j = 0; j < 8; ++j) {
    o0[j] = (f16)((float)o0[j] + acc[j]);
    o1[j] = (f16)((float)o1[j] + acc[j + 8]);
  }
  *(f16x8*)op = o0;
  *(f16x8*)(op + 8) = o1;
}

// -------------- GroupNorm(heads) * ln, then * silu(g) -> f16 y (in-place ok) --------------
__global__ __launch_bounds__(256) void k_gnorm(const f16* __restrict__ xo, const f16* __restrict__ g,
    const float* __restrict__ ln_w, const float* __restrict__ ln_b, f16* __restrict__ y) {
  int t = blockIdx.x;
  int tid = threadIdx.x;
  int c = tid * 8;
  f16x8 xv8 = *(const f16x8*)(xo + (size_t)t * NC + c);
  float xv[8];
#pragma unroll
  for (int j = 0; j < 8; ++j) xv[j] = (float)xv8[j];
  float s = 0.f, ss = 0.f;
#pragma unroll
  for (int j = 0; j < 8; ++j) { s += xv[j]; ss += xv[j] * xv[j]; }
  s += __shfl_xor(s, 1); ss += __shfl_xor(ss, 1);
  s += __shfl_xor(s, 2); ss += __shfl_xor(ss, 2);
  s += __shfl_xor(s, 4); ss += __shfl_xor(ss, 4);
  float mu = s * (1.0f / 64.0f);
  float var = ss * (1.0f / 64.0f) - mu * mu;
  float rstd = rsqrtf(var + GN_EPS);
  f16x8 gv = *(const f16x8*)(g + (size_t)t * NC + c);
  f16x8 ov;
#pragma unroll
  for (int j = 0; j < 8; ++j) {
    float xn = (xv[j] - mu) * rstd * ln_w[c + j] + ln_b[c + j];
    ov[j] = (f16)(xn * (float)gv[j]);
  }
  *(f16x8*)(y + (size_t)t * NC + c) = ov;
}

extern "C" void kernel_launch(void* const* d_in, const int* in_sizes, int n_in,
                              void* d_out, int out_size, void* d_ws, size_t ws_size,
                              hipStream_t stream) {
  const float* hs = (const float*)d_in[0];
  const int* positions = (const int*)d_in[1];
  const float* kvstate = (const float*)d_in[2];
  const float* shift_st = (const float*)d_in[3];
  const float* maa_x = (const float*)d_in[4];
  const float* maa_w = (const float*)d_in[5];
  const float* maa_k = (const float*)d_in[6];
  const float* maa_v = (const float*)d_in[7];
  const float* maa_r = (const float*)d_in[8];
  const float* maa_g = (const float*)d_in[9];
  const float* maa_w1 = (const float*)d_in[10];
  const float* maa_w2 = (const float*)d_in[11];
  const float* time_decay = (const float*)d_in[12];
  const float* decay_w1 = (const float*)d_in[13];
  const float* decay_w2 = (const float*)d_in[14];
  const float* faaaa = (const float*)d_in[15];
  const float* W_r = (const float*)d_in[16];
  const float* W_k = (const float*)d_in[17];
  const float* W_v = (const float*)d_in[18];
  const float* W_g = (const float*)d_in[19];
  const float* W_o = (const float*)d_in[20];
  const float* ln_w = (const float*)d_in[21];
  const float* ln_b = (const float*)d_in[22];

  char* ws = (char*)d_ws;
  size_t off = 0;
  auto alloc = [&](size_t n) {
    char* p = ws + off;
    off += (n + 255) & ~(size_t)255;
    return p;
  };
  // persistent small (~8.4 MB)
  f16* w1t_hi = (f16*)alloc(160ull * 2048 * 2);
  f16* w1t_lo = (f16*)alloc(160ull * 2048 * 2);
  f16* w2t_hi = (f16*)alloc(5ull * 2048 * 32 * 2);
  f16* w2t_lo = (f16*)alloc(5ull * 2048 * 32 * 2);
  f16* dw1t_hi = (f16*)alloc(64ull * 2048 * 2);
  f16* dw1t_lo = (f16*)alloc(64ull * 2048 * 2);
  f16* dw2t_hi = (f16*)alloc(2048ull * 64 * 2);
  f16* dw2t_lo = (f16*)alloc(2048ull * 64 * 2);
  float* mixb = (float*)alloc(4096ull * 160 * 4);
  f16* wd1h = (f16*)alloc(4096ull * 64 * 2);
  f16* wd1l = (f16*)alloc(4096ull * 64 * 2);
  // arena -> total ~225.4 MB (< 229.6 proven-safe)
  char* R_A = alloc(4096ull * 2048 * 4);   // xxx hi/lo -> tdin hi/lo -> ewbuf
  char* R_B = alloc(4096ull * 2048 * 4);   // rbuf / r~
  char* R_C = alloc(4096ull * 2048 * 4);   // kbuf
  char* R_D = alloc(4096ull * 2048 * 4);   // vbuf
  char* R_E = alloc(4096ull * 2048 * 2);   // W-stage -> obuf(f16) (in-place gnorm)
  char* F12 = alloc(4096ull * 2048 * 4);   // kx | vx  -> Ebuf + Dbuf
  char* F3 = alloc(4096ull * 2048 * 2);    // rx -> gbuf
  char* F4 = alloc(4096ull * 2048 * 2);    // gx -> wt_o

  f16* xh = (f16*)R_A;
  f16* xl = (f16*)(R_A + 4096ull * 2048 * 2);
  f16* th = (f16*)R_A;                      // tdin hi (xxx dead after mix1)
  f16* tl = (f16*)(R_A + 4096ull * 2048 * 2);
  float* ewbuf = (float*)R_A;               // after wd1 consumed tdin
  float* rbuf = (float*)R_B;
  float* kbuf = (float*)R_C;
  float* vbuf = (float*)R_D;
  f16* wstage = (f16*)R_E;
  f16* obuf = (f16*)R_E;
  f16* kx = (f16*)F12;
  f16* vx = (f16*)(F12 + 4096ull * 2048 * 2);
  float* Ebuf = (float*)F12;                     // 256*7*4096*4 = 29.36 MB
  float* Dbuf = (float*)(F12 + 29360128);        // 256*8*64*4 = 0.52 MB
  f16* rx = (f16*)F3;
  f16* gbuf = (f16*)F3;
  f16* gx = (f16*)F4;
  f16* wt_o = (f16*)F4;

  dim3 tb(32, 8);
  // small split transposes
  k_transpose_split<<<dim3(5, 64), tb, 0, stream>>>(maa_w1, w1t_hi, w1t_lo, 2048, 160);
  k_tsplit_w2<<<dim3(64, 1, 5), tb, 0, stream>>>(maa_w2, w2t_hi, w2t_lo);
  k_transpose_split<<<dim3(2, 64), tb, 0, stream>>>(decay_w1, dw1t_hi, dw1t_lo, 2048, 64);
  k_transpose_split<<<dim3(64, 2), tb, 0, stream>>>(decay_w2, dw2t_hi, dw2t_lo, 64, 2048);

  // pre-scan chain
  k_xxx<<<8192, 256, 0, stream>>>(hs, shift_st, positions, maa_x, xh, xl);
  k_mix1_split<<<dim3(256, 10), 64, 0, stream>>>(xh, xl, w1t_hi, w1t_lo, mixb);
  k_tmp5_split<<<dim3(256, 128), 64, 0, stream>>>(mixb, w2t_hi, w2t_lo, hs, shift_st,
      positions, maa_w, maa_k, maa_v, maa_r, maa_g, th, tl, kx, vx, rx, gx);
  k_wd1_split<<<dim3(256, 4), 64, 0, stream>>>(th, tl, dw1t_hi, dw1t_lo, wd1h, wd1l);
  k_wdecay_split<<<dim3(256, 128), 64, 0, stream>>>(wd1h, wd1l, dw2t_hi, dw2t_lo,
                                                    time_decay, ewbuf);

  // big projections (plain f16 MFMA, fp32 outputs for r/k/v)
  dim3 gg(2048 / GBN, 4096 / GBM);
  k_transpose_cast<<<dim3(64, 64), tb, 0, stream>>>(W_r, wstage, 2048, 2048);
  k_gemm_big<0><<<gg, 256, 0, stream>>>(rx, wstage, rbuf, nullptr, 2048);
  k_transpose_cast<<<dim3(64, 64), tb, 0, stream>>>(W_k, wstage, 2048, 2048);
  k_gemm_big<0><<<gg, 256, 0, stream>>>(kx, wstage, kbuf, nullptr, 2048);
  k_transpose_cast<<<dim3(64, 64), tb, 0, stream>>>(W_v, wstage, 2048, 2048);
  k_gemm_big<0><<<gg, 256, 0, stream>>>(vx, wstage, vbuf, nullptr, 2048);
  k_transpose_cast<<<dim3(64, 64), tb, 0, stream>>>(W_g, wstage, 2048, 2048);
  k_gemm_big<2><<<gg, 256, 0, stream>>>(gx, wstage, nullptr, gbuf, 2048);
  k_transpose_cast<<<dim3(64, 64), tb, 0, stream>>>(W_o, wt_o, 2048, 2048);  // gx dead

  // chunked scan (8 chunks of 64, 1 wave per chunk) + exact recombination
  k_scanE<<<2048, 64, 0, stream>>>(rbuf, kbuf, vbuf, ewbuf, kvstate, positions, faaaa,
                                   obuf, rbuf, Ebuf, Dbuf);
  k_comb<<<256, 256, 0, stream>>>(Ebuf, Dbuf);
  k_fix<<<1792, 256, 0, stream>>>(rbuf, Ebuf, obuf);

  // groupnorm * silu(g) (in-place) then output projection
  k_gnorm<<<4096, 256, 0, stream>>>(obuf, gbuf, ln_w, ln_b, obuf);
  k_gemm_big<0><<<gg, 256, 0, stream>>>(obuf, wt_o, (float*)d_out, nullptr, 2048);
}

// Round 17
// 635.635 us; speedup vs baseline: 1.0863x; 1.0863x over previous
//
#include <hip/hip_runtime.h>
#include <cmath>

#define NB 8
#define NT 512
#define NC 2048
#define NH 32
#define NZ 64
static constexpr float GN_EPS = 1e-5f * 64.0f;

typedef _Float16 f16;
typedef __attribute__((ext_vector_type(8))) _Float16 f16x8;
typedef __attribute__((ext_vector_type(4))) _Float16 f16x4;
typedef __attribute__((ext_vector_type(4))) float f4;

static __device__ __forceinline__ void gload16(const void* gp, void* lp) {
  __builtin_amdgcn_global_load_lds(
      (const __attribute__((address_space(1))) void*)gp,
      (__attribute__((address_space(3))) void*)lp, 16, 0, 0);
}

// ---------------- transpose + cast fp32 [R,Cc] -> f16 [Cc,R] ----------------
__global__ void k_transpose_cast(const float* __restrict__ in, f16* __restrict__ out,
                                 int R, int Cc) {
  __shared__ float tile[32][33];
  int c0 = blockIdx.x * 32, r0 = blockIdx.y * 32;
  int tx = threadIdx.x, ty = threadIdx.y;
#pragma unroll
  for (int i = 0; i < 4; ++i)
    tile[ty + i * 8][tx] = in[(size_t)(r0 + ty + i * 8) * Cc + c0 + tx];
  __syncthreads();
#pragma unroll
  for (int i = 0; i < 4; ++i)
    out[(size_t)(c0 + ty + i * 8) * R + r0 + tx] = (f16)tile[tx][ty + i * 8];
}

// ------------- transpose + hi/lo split fp32 [R,Cc] -> f16 [Cc,R] x2 -------------
__global__ void k_transpose_split(const float* __restrict__ in, f16* __restrict__ ohi,
                                  f16* __restrict__ olo, int R, int Cc) {
  __shared__ float tile[32][33];
  int c0 = blockIdx.x * 32, r0 = blockIdx.y * 32;
  int tx = threadIdx.x, ty = threadIdx.y;
#pragma unroll
  for (int i = 0; i < 4; ++i)
    tile[ty + i * 8][tx] = in[(size_t)(r0 + ty + i * 8) * Cc + c0 + tx];
  __syncthreads();
#pragma unroll
  for (int i = 0; i < 4; ++i) {
    float v = tile[tx][ty + i * 8];
    f16 h = (f16)v;
    size_t o = (size_t)(c0 + ty + i * 8) * R + r0 + tx;
    ohi[o] = h;
    olo[o] = (f16)(v - (float)h);
  }
}

// ---- five maa_w2 transposes in one launch: z = feature, [32,2048] -> [2048,32] ----
__global__ void k_tsplit_w2(const float* __restrict__ in0, f16* __restrict__ ohi0,
                            f16* __restrict__ olo0) {
  __shared__ float tile[32][33];
  int f = blockIdx.z;
  const float* in = in0 + (size_t)f * 32 * 2048;
  f16* ohi = ohi0 + (size_t)f * 2048 * 32;
  f16* olo = olo0 + (size_t)f * 2048 * 32;
  int c0 = blockIdx.x * 32;
  int tx = threadIdx.x, ty = threadIdx.y;
#pragma unroll
  for (int i = 0; i < 4; ++i)
    tile[ty + i * 8][tx] = in[(size_t)(ty + i * 8) * 2048 + c0 + tx];
  __syncthreads();
#pragma unroll
  for (int i = 0; i < 4; ++i) {
    float v = tile[tx][ty + i * 8];
    f16 h = (f16)v;
    size_t o = (size_t)(c0 + ty + i * 8) * 32 + tx;
    ohi[o] = h;
    olo[o] = (f16)(v - (float)h);
  }
}

// -------- xxx = x + (shift - x) * maa_x  -> f16 hi/lo planes --------
__global__ void k_xxx(const float* __restrict__ hs, const float* __restrict__ shift_st,
                      const int* __restrict__ positions, const float* __restrict__ maa_x,
                      f16* __restrict__ xh, f16* __restrict__ xl) {
  int i = blockIdx.x * blockDim.x + threadIdx.x;
  int idx = i * 4;
  int c = idx & (NC - 1);
  int t = idx >> 11;
  int b = t >> 9;
  float er = (positions[b * NT] == 0) ? expf(-100.0f) : 1.0f;
  const float4 x = *(const float4*)(hs + idx);
  const float4 sh = *(const float4*)(shift_st + b * NC + c);
  const float4 mx = *(const float4*)(maa_x + c);
  float ov[4];
  ov[0] = x.x + (sh.x * er - x.x) * mx.x;
  ov[1] = x.y + (sh.y * er - x.y) * mx.y;
  ov[2] = x.z + (sh.z * er - x.z) * mx.z;
  ov[3] = x.w + (sh.w * er - x.w) * mx.w;
  f16x4 h4, l4;
#pragma unroll
  for (int j = 0; j < 4; ++j) {
    f16 h = (f16)ov[j];
    h4[j] = h;
    l4[j] = (f16)(ov[j] - (float)h);
  }
  *(f16x4*)(xh + idx) = h4;
  *(f16x4*)(xl + idx) = l4;
}

static __device__ __forceinline__ void split4(const float4 v, int base, f16x8& hi, f16x8& lo) {
  float x[4] = {v.x, v.y, v.z, v.w};
#pragma unroll
  for (int j = 0; j < 4; ++j) {
    f16 h = (f16)x[j];
    hi[base + j] = h;
    lo[base + j] = (f16)(x[j] - (float)h);
  }
}

// ---- mix1: mixb = tanh(xxx @ w1)  M=4096 N=160 K=2048, A hi/lo planes, fp32 out ----
__global__ __launch_bounds__(64) void k_mix1_split(const f16* __restrict__ Ah,
                                                   const f16* __restrict__ Al,
                                                   const f16* __restrict__ Bhi,
                                                   const f16* __restrict__ Blo,
                                                   float* __restrict__ out) {
  int m0 = blockIdx.x * 16, n0 = blockIdx.y * 16;
  int lane = threadIdx.x, lr = lane & 15, kq = lane >> 4;
  f4 acc = {0.f, 0.f, 0.f, 0.f};
  const f16* ah0 = Ah + (size_t)(m0 + lr) * 2048 + kq * 8;
  const f16* al0 = Al + (size_t)(m0 + lr) * 2048 + kq * 8;
  const f16* bh0 = Bhi + (size_t)(n0 + lr) * 2048 + kq * 8;
  const f16* bl0 = Blo + (size_t)(n0 + lr) * 2048 + kq * 8;
  for (int k0 = 0; k0 < 2048; k0 += 32) {
    f16x8 ah = *(const f16x8*)(ah0 + k0);
    f16x8 al = *(const f16x8*)(al0 + k0);
    f16x8 bh = *(const f16x8*)(bh0 + k0);
    f16x8 bl = *(const f16x8*)(bl0 + k0);
    acc = __builtin_amdgcn_mfma_f32_16x16x32_f16(ah, bh, acc, 0, 0, 0);
    acc = __builtin_amdgcn_mfma_f32_16x16x32_f16(ah, bl, acc, 0, 0, 0);
    acc = __builtin_amdgcn_mfma_f32_16x16x32_f16(al, bh, acc, 0, 0, 0);
  }
#pragma unroll
  for (int r = 0; r < 4; ++r)
    out[(size_t)(m0 + kq * 4 + r) * 160 + n0 + lr] = tanhf(acc[r]);
}

// ---- tmp5: mix2 (K=32 per feature, split) + fused 5-way mix epilogue ----
__global__ __launch_bounds__(64) void k_tmp5_split(const float* __restrict__ mixb,
    const f16* __restrict__ Bhi, const f16* __restrict__ Blo,
    const float* __restrict__ hs, const float* __restrict__ shift_st,
    const int* __restrict__ positions,
    const float* __restrict__ maa_w, const float* __restrict__ maa_k,
    const float* __restrict__ maa_v, const float* __restrict__ maa_r,
    const float* __restrict__ maa_g,
    f16* __restrict__ th, f16* __restrict__ tl, f16* __restrict__ kx,
    f16* __restrict__ vx, f16* __restrict__ rx, f16* __restrict__ gx) {
  int m0 = blockIdx.x * 16, n0 = blockIdx.y * 16;
  int lane = threadIdx.x, lr = lane & 15, kq = lane >> 4;
  f4 acc[5];
#pragma unroll
  for (int f = 0; f < 5; ++f) acc[f] = (f4){0.f, 0.f, 0.f, 0.f};
  const float* ap = mixb + (size_t)(m0 + lr) * 160 + kq * 8;
#pragma unroll
  for (int f = 0; f < 5; ++f) {
    f16x8 ah, al;
    split4(*(const float4*)(ap + f * 32), 0, ah, al);
    split4(*(const float4*)(ap + f * 32 + 4), 4, ah, al);
    size_t bi = ((size_t)f * 2048 + n0 + lr) * 32 + kq * 8;
    f16x8 bh = *(const f16x8*)(Bhi + bi);
    f16x8 bl = *(const f16x8*)(Blo + bi);
    acc[f] = __builtin_amdgcn_mfma_f32_16x16x32_f16(ah, bh, acc[f], 0, 0, 0);
    acc[f] = __builtin_amdgcn_mfma_f32_16x16x32_f16(ah, bl, acc[f], 0, 0, 0);
    acc[f] = __builtin_amdgcn_mfma_f32_16x16x32_f16(al, bh, acc[f], 0, 0, 0);
  }
  int c = n0 + lr;
  float mw = maa_w[c], mk = maa_k[c], mv = maa_v[c], mr = maa_r[c], mg = maa_g[c];
#pragma unroll
  for (int r = 0; r < 4; ++r) {
    int t = m0 + kq * 4 + r;
    int b = t >> 9;
    float er = (positions[b * NT] == 0) ? expf(-100.0f) : 1.0f;
    float x = hs[(size_t)t * NC + c];
    float xxv = shift_st[b * NC + c] * er - x;
    size_t oi = (size_t)t * NC + c;
    float tv = x + xxv * (mw + acc[0][r]);
    f16 hh = (f16)tv;
    th[oi] = hh;
    tl[oi] = (f16)(tv - (float)hh);
    kx[oi] = (f16)(x + xxv * (mk + acc[1][r]));
    vx[oi] = (f16)(x + xxv * (mv + acc[2][r]));
    rx[oi] = (f16)(x + xxv * (mr + acc[3][r]));
    gx[oi] = (f16)(x + xxv * (mg + acc[4][r]));
  }
}

// ---- wd1 = tanh(tdin @ dw1)  M=4096 N=64 K=2048, A hi/lo planes, out hi/lo ----
__global__ __launch_bounds__(64) void k_wd1_split(const f16* __restrict__ Ah,
                                                  const f16* __restrict__ Al,
                                                  const f16* __restrict__ Bhi,
                                                  const f16* __restrict__ Blo,
                                                  f16* __restrict__ wh,
                                                  f16* __restrict__ wl) {
  int m0 = blockIdx.x * 16, n0 = blockIdx.y * 16;
  int lane = threadIdx.x, lr = lane & 15, kq = lane >> 4;
  f4 acc = {0.f, 0.f, 0.f, 0.f};
  const f16* ah0 = Ah + (size_t)(m0 + lr) * 2048 + kq * 8;
  const f16* al0 = Al + (size_t)(m0 + lr) * 2048 + kq * 8;
  const f16* bh0 = Bhi + (size_t)(n0 + lr) * 2048 + kq * 8;
  const f16* bl0 = Blo + (size_t)(n0 + lr) * 2048 + kq * 8;
  for (int k0 = 0; k0 < 2048; k0 += 32) {
    f16x8 ah = *(const f16x8*)(ah0 + k0);
    f16x8 al = *(const f16x8*)(al0 + k0);
    f16x8 bh = *(const f16x8*)(bh0 + k0);
    f16x8 bl = *(const f16x8*)(bl0 + k0);
    acc = __builtin_amdgcn_mfma_f32_16x16x32_f16(ah, bh, acc, 0, 0, 0);
    acc = __builtin_amdgcn_mfma_f32_16x16x32_f16(ah, bl, acc, 0, 0, 0);
    acc = __builtin_amdgcn_mfma_f32_16x16x32_f16(al, bh, acc, 0, 0, 0);
  }
#pragma unroll
  for (int r = 0; r < 4; ++r) {
    float tv = tanhf(acc[r]);
    f16 hh = (f16)tv;
    size_t oi = (size_t)(m0 + kq * 4 + r) * 64 + n0 + lr;
    wh[oi] = hh;
    wl[oi] = (f16)(tv - (float)hh);
  }
}

// ---- w = -exp(time_decay + wd1 @ dw2)  M=4096 N=2048 K=64, A hi/lo, fp32 out ----
__global__ __launch_bounds__(64) void k_wdecay_split(const f16* __restrict__ Ah,
                                                     const f16* __restrict__ Al,
                                                     const f16* __restrict__ Bhi,
                                                     const f16* __restrict__ Blo,
                                                     const float* __restrict__ time_decay,
                                                     float* __restrict__ wout) {
  int m0 = blockIdx.x * 16, n0 = blockIdx.y * 16;
  int lane = threadIdx.x, lr = lane & 15, kq = lane >> 4;
  f4 acc = {0.f, 0.f, 0.f, 0.f};
#pragma unroll
  for (int kk = 0; kk < 2; ++kk) {
    size_t ai = (size_t)(m0 + lr) * 64 + kk * 32 + kq * 8;
    f16x8 ah = *(const f16x8*)(Ah + ai);
    f16x8 al = *(const f16x8*)(Al + ai);
    size_t bi = (size_t)(n0 + lr) * 64 + kk * 32 + kq * 8;
    f16x8 bh = *(const f16x8*)(Bhi + bi);
    f16x8 bl = *(const f16x8*)(Blo + bi);
    acc = __builtin_amdgcn_mfma_f32_16x16x32_f16(ah, bh, acc, 0, 0, 0);
    acc = __builtin_amdgcn_mfma_f32_16x16x32_f16(ah, bl, acc, 0, 0, 0);
    acc = __builtin_amdgcn_mfma_f32_16x16x32_f16(al, bh, acc, 0, 0, 0);
  }
  int c = n0 + lr;
  float td = time_decay[c];
#pragma unroll
  for (int r = 0; r < 4; ++r) {
    int t = m0 + kq * 4 + r;
    wout[(size_t)t * NC + c] = -expf(td + acc[r]);
  }
}

// ---- f16 big GEMM 128x128x64: counted-vmcnt dbuf pipeline (T4) + XOR swizzle ----
#define GBM 128
#define GBN 128
#define GBK 64

template <int EPI>
__global__ __launch_bounds__(256) void k_gemm_big(const f16* __restrict__ A,
                                                  const f16* __restrict__ Bt,
                                                  float* __restrict__ Cf,
                                                  f16* __restrict__ Cb, int K) {
  __shared__ __align__(16) f16 As[2][GBM][GBK];
  __shared__ __align__(16) f16 Bs[2][GBN][GBK];
  int nwg = gridDim.x * gridDim.y;
  int wg = blockIdx.y * gridDim.x + blockIdx.x;
  int swz = (wg & 7) * (nwg >> 3) + (wg >> 3);
  int n0 = (swz % gridDim.x) * GBN;
  int m0 = (swz / gridDim.x) * GBM;
  int tid = threadIdx.x;
  int wid = tid >> 6, lane = tid & 63;
  int wr = wid >> 1, wc = wid & 1;
  int lr = lane & 15, kq = lane >> 4;
  int sw = lr & 7;
  int gunit = (lane & 7) ^ (lane >> 3);
  const f16* aL = A + (size_t)(m0 + wid * 32 + (lane >> 3)) * K + gunit * 8;
  const f16* bL = Bt + (size_t)(n0 + wid * 32 + (lane >> 3)) * K + gunit * 8;
  f4 acc[4][4];
#pragma unroll
  for (int m = 0; m < 4; ++m)
#pragma unroll
    for (int n = 0; n < 4; ++n) acc[m][n] = (f4){0.f, 0.f, 0.f, 0.f};

  auto stage = [&](int buf, int t) {
    int k0 = t * GBK;
#pragma unroll
    for (int i = 0; i < 4; ++i) {
      gload16(aL + k0 + (size_t)i * 8 * K, &As[buf][wid * 32 + i * 8][0]);
      gload16(bL + k0 + (size_t)i * 8 * K, &Bs[buf][wid * 32 + i * 8][0]);
    }
  };

  int niter = K / GBK;
  stage(0, 0);
  stage(1, 1);
  for (int it = 0; it < niter; ++it) {
    if (it == niter - 1)
      asm volatile("s_waitcnt vmcnt(0)" ::: "memory");
    else
      asm volatile("s_waitcnt vmcnt(8)" ::: "memory");
    __builtin_amdgcn_sched_barrier(0);
    __builtin_amdgcn_s_barrier();  // all waves' tile-it data resident
    int cur = it & 1;
#pragma unroll
    for (int kk = 0; kk < 2; ++kk) {
      f16x8 af[4], bfv[4];
      int un = ((kk * 4 + kq) ^ sw) * 8;
#pragma unroll
      for (int m = 0; m < 4; ++m)
        af[m] = *(const f16x8*)&As[cur][wr * 64 + m * 16 + lr][un];
#pragma unroll
      for (int n = 0; n < 4; ++n)
        bfv[n] = *(const f16x8*)&Bs[cur][wc * 64 + n * 16 + lr][un];
#pragma unroll
      for (int m = 0; m < 4; ++m)
#pragma unroll
        for (int n = 0; n < 4; ++n)
          acc[m][n] = __builtin_amdgcn_mfma_f32_16x16x32_f16(af[m], bfv[n], acc[m][n], 0, 0, 0);
    }
    __builtin_amdgcn_s_barrier();  // all reads of buf[cur] done
    if (it + 2 < niter) stage(cur, it + 2);
  }
#pragma unroll
  for (int m = 0; m < 4; ++m) {
    int row0 = m0 + wr * 64 + m * 16 + kq * 4;
#pragma unroll
    for (int n = 0; n < 4; ++n) {
      int col = n0 + wc * 64 + n * 16 + lr;
#pragma unroll
      for (int r = 0; r < 4; ++r) {
        float v = acc[m][n][r];
        size_t oi = (size_t)(row0 + r) * NC + col;
        if (EPI == 0) {
          Cf[oi] = v;
        } else {
          float s = v / (1.0f + expf(-v));
          Cb[oi] = (f16)s;
        }
      }
    }
  }
}

// ------------- chunked WKV scan: ONE WAVE per (b,h,chunk), L=64 -------------
// LDS-staged pipeline: groups of 4 steps; 4 gload16 per group (r,k,w,v),
// counted vmcnt(4) keeps next group's loads in flight. No prefetch VGPRs.
// (measured-good: 88-89 us, VGPR 116, thrice confirmed)
__global__ __launch_bounds__(64) void k_scanD(
    const float* rb, const float* __restrict__ kb,
    const float* __restrict__ vb, const float* __restrict__ wb,
    const float* __restrict__ kvstate, const int* __restrict__ positions,
    const float* __restrict__ faaaa, f16* __restrict__ o,
    float* rtil, float* __restrict__ Ebuf, float* __restrict__ Dbuf) {
  int blk = blockIdx.x;
  int bh = blk >> 3, c = blk & 7;
  int b = bh >> 5, h = bh & 31;
  int zz = threadIdx.x;
  __shared__ __align__(16) float stg[2][4][4][64];  // [buf][r,k,w,v][step][ch]
  __shared__ __align__(16) float shE[4][64];
  float S[64];
  if (c == 0) {
    const float* S0 = kvstate + (size_t)bh * 4096;
#pragma unroll
    for (int j = 0; j < 64; ++j) S[j] = S0[j * 64 + zz];
  } else {
#pragma unroll
    for (int j = 0; j < 64; ++j) S[j] = 0.f;
  }
  float u = faaaa[h * 64 + zz];
  float reset = (positions[b * NT] == 0) ? -100.0f : 0.0f;
  const int row0 = b * NT + c * 64;
  const int lrow = zz >> 4, lcol = (zz & 15) * 4;

  auto stage = [&](int buf, int T) {
    size_t goff = (size_t)(row0 + T + lrow) * NC + h * 64 + lcol;
    gload16(rb + goff, &stg[buf][0][0][0]);
    gload16(kb + goff, &stg[buf][1][0][0]);
    gload16(wb + goff, &stg[buf][2][0][0]);
    gload16(vb + goff, &stg[buf][3][0][0]);
  };
  stage(0, 0);
  stage(1, 4);
  float Pw = 1.0f;
  for (int g = 0; g < 16; ++g) {
    if (g == 15)
      asm volatile("s_waitcnt vmcnt(0)" ::: "memory");
    else
      asm volatile("s_waitcnt vmcnt(4)" ::: "memory");
    __builtin_amdgcn_sched_barrier(0);
    __syncthreads();  // group-g data resident; prev group's shE reads done
    int cur = g & 1;
    float ew[4];
#pragma unroll
    for (int j = 0; j < 4; ++j) {
      float ww = stg[cur][2][j][zz];
      if (c == 0 && g == 0 && j == 0) ww += reset;
      ew[j] = expf(ww);
      shE[j][zz] = ew[j];
    }
    __syncthreads();  // shE ready
#pragma unroll
    for (int j = 0; j < 4; ++j) {
      int t = g * 4 + j;
      size_t rowoff = (size_t)(row0 + t) * NC + h * 64;
      float vr = stg[cur][0][j][zz];
      float vk = stg[cur][1][j][zz];
      float vv = stg[cur][3][j][zz];
      float q = vr * u * vk;
      q += __shfl_xor(q, 1);  q += __shfl_xor(q, 2);  q += __shfl_xor(q, 4);
      q += __shfl_xor(q, 8);  q += __shfl_xor(q, 16); q += __shfl_xor(q, 32);
      if (c > 0) rtil[rowoff + zz] = vr * Pw;
      Pw *= ew[j];
      float oacc = vv * q;
#pragma unroll
      for (int k0 = 0; k0 < 64; k0 += 4) {
        f4 r4 = *(const f4*)&stg[cur][0][j][k0];
        f4 e4 = *(const f4*)&shE[j][k0];
        f4 k4 = *(const f4*)&stg[cur][1][j][k0];
#pragma unroll
        for (int jj = 0; jj < 4; ++jj) {
          oacc = fmaf(r4[jj], S[k0 + jj], oacc);
          S[k0 + jj] = fmaf(e4[jj], S[k0 + jj], k4[jj] * vv);
        }
      }
      o[rowoff + zz] = (f16)oacc;
    }
    if (g + 2 < 16) stage(cur, (g + 2) * 4);
  }
  if (c < 7) {
    float* E = Ebuf + ((size_t)bh * 7 + c) * 4096;
#pragma unroll
    for (int j = 0; j < 64; ++j) E[j * 64 + zz] = S[j];
  }
  Dbuf[((size_t)bh * 8 + c) * 64 + zz] = Pw;
}

// ---- combine: slot(c-1) := true chunk-start state S_c,  c=1..7 (in-place walk) ----
__global__ __launch_bounds__(256) void k_comb(float* __restrict__ Ebuf,
                                              const float* __restrict__ Dbuf) {
  int bh = blockIdx.x, tid = threadIdx.x;
  int k = tid >> 2, v0 = (tid & 3) * 16;
  float* base = Ebuf + (size_t)bh * 7 * 4096;
  float S[16];
#pragma unroll
  for (int j = 0; j < 16; ++j) S[j] = base[k * 64 + v0 + j];
  for (int c = 2; c <= 7; ++c) {
    float d = Dbuf[((size_t)bh * 8 + (c - 1)) * 64 + k];
    float* slot = base + (size_t)(c - 1) * 4096;
#pragma unroll
    for (int j = 0; j < 16; ++j) {
      S[j] = fmaf(d, S[j], slot[k * 64 + v0 + j]);
      slot[k * 64 + v0 + j] = S[j];
    }
  }
}

// ---- fixup: o[c*64+t] += r~_t^T S_c  (block per (bh, c-1)), f16 RMW ----
__global__ __launch_bounds__(256) void k_fix(const float* __restrict__ rtil,
                                             const float* __restrict__ Ebuf,
                                             f16* __restrict__ o) {
  int blk = blockIdx.x;
  int bh = blk / 7, cm = blk - bh * 7;
  int c = cm + 1;
  int b = bh >> 5, h = bh & 31;
  __shared__ float Rs[64][65];
  __shared__ float Ss[64][65];
  int tid = threadIdx.x;
  const float* rsrc = rtil + ((size_t)(b * NT) + c * 64) * NC + h * NZ;
  const float* ssrc = Ebuf + ((size_t)bh * 7 + cm) * 4096;
#pragma unroll
  for (int q = 0; q < 4; ++q) {
    int li = tid * 4 + q;
    int rr = li >> 4, cc = (li & 15) * 4;
    float4 x = *(const float4*)(rsrc + (size_t)rr * NC + cc);
    Rs[rr][cc] = x.x; Rs[rr][cc + 1] = x.y; Rs[rr][cc + 2] = x.z; Rs[rr][cc + 3] = x.w;
    float4 y = *(const float4*)(ssrc + rr * 64 + cc);
    Ss[rr][cc] = y.x; Ss[rr][cc + 1] = y.y; Ss[rr][cc + 2] = y.z; Ss[rr][cc + 3] = y.w;
  }
  __syncthreads();
  int t = tid >> 2, v0 = (tid & 3) * 16;
  float acc[16];
#pragma unroll
  for (int j = 0; j < 16; ++j) acc[j] = 0.f;
  for (int k = 0; k < 64; ++k) {
    float rv = Rs[t][k];
#pragma unroll
    for (int j = 0; j < 16; ++j) acc[j] = fmaf(rv, Ss[k][v0 + j], acc[j]);
  }
  f16* op = o + ((size_t)(b * NT) + c * 64 + t) * NC + h * NZ + v0;
  f16x8 o0 = *(f16x8*)op, o1 = *(f16x8*)(op + 8);
#pragma unroll
  for (int j = 0; j < 8; ++j) {
    o0[j] = (f16)((float)o0[j] + acc[j]);
    o1[j] = (f16)((float)o1[j] + acc[j + 8]);
  }
  *(f16x8*)op = o0;
  *(f16x8*)(op + 8) = o1;
}

// -------------- GroupNorm(heads) * ln, then * silu(g) -> f16 y (in-place ok) --------------
__global__ __launch_bounds__(256) void k_gnorm(const f16* __restrict__ xo, const f16* __restrict__ g,
    const float* __restrict__ ln_w, const float* __restrict__ ln_b, f16* __restrict__ y) {
  int t = blockIdx.x;
  int tid = threadIdx.x;
  int c = tid * 8;
  f16x8 xv8 = *(const f16x8*)(xo + (size_t)t * NC + c);
  float xv[8];
#pragma unroll
  for (int j = 0; j < 8; ++j) xv[j] = (float)xv8[j];
  float s = 0.f, ss = 0.f;
#pragma unroll
  for (int j = 0; j < 8; ++j) { s += xv[j]; ss += xv[j] * xv[j]; }
  s += __shfl_xor(s, 1); ss += __shfl_xor(ss, 1);
  s += __shfl_xor(s, 2); ss += __shfl_xor(ss, 2);
  s += __shfl_xor(s, 4); ss += __shfl_xor(ss, 4);
  float mu = s * (1.0f / 64.0f);
  float var = ss * (1.0f / 64.0f) - mu * mu;
  float rstd = rsqrtf(var + GN_EPS);
  f16x8 gv = *(const f16x8*)(g + (size_t)t * NC + c);
  f16x8 ov;
#pragma unroll
  for (int j = 0; j < 8; ++j) {
    float xn = (xv[j] - mu) * rstd * ln_w[c + j] + ln_b[c + j];
    ov[j] = (f16)(xn * (float)gv[j]);
  }
  *(f16x8*)(y + (size_t)t * NC + c) = ov;
}

extern "C" void kernel_launch(void* const* d_in, const int* in_sizes, int n_in,
                              void* d_out, int out_size, void* d_ws, size_t ws_size,
                              hipStream_t stream) {
  const float* hs = (const float*)d_in[0];
  const int* positions = (const int*)d_in[1];
  const float* kvstate = (const float*)d_in[2];
  const float* shift_st = (const float*)d_in[3];
  const float* maa_x = (const float*)d_in[4];
  const float* maa_w = (const float*)d_in[5];
  const float* maa_k = (const float*)d_in[6];
  const float* maa_v = (const float*)d_in[7];
  const float* maa_r = (const float*)d_in[8];
  const float* maa_g = (const float*)d_in[9];
  const float* maa_w1 = (const float*)d_in[10];
  const float* maa_w2 = (const float*)d_in[11];
  const float* time_decay = (const float*)d_in[12];
  const float* decay_w1 = (const float*)d_in[13];
  const float* decay_w2 = (const float*)d_in[14];
  const float* faaaa = (const float*)d_in[15];
  const float* W_r = (const float*)d_in[16];
  const float* W_k = (const float*)d_in[17];
  const float* W_v = (const float*)d_in[18];
  const float* W_g = (const float*)d_in[19];
  const float* W_o = (const float*)d_in[20];
  const float* ln_w = (const float*)d_in[21];
  const float* ln_b = (const float*)d_in[22];

  char* ws = (char*)d_ws;
  size_t off = 0;
  auto alloc = [&](size_t n) {
    char* p = ws + off;
    off += (n + 255) & ~(size_t)255;
    return p;
  };
  // persistent small (~8.4 MB)
  f16* w1t_hi = (f16*)alloc(160ull * 2048 * 2);
  f16* w1t_lo = (f16*)alloc(160ull * 2048 * 2);
  f16* w2t_hi = (f16*)alloc(5ull * 2048 * 32 * 2);
  f16* w2t_lo = (f16*)alloc(5ull * 2048 * 32 * 2);
  f16* dw1t_hi = (f16*)alloc(64ull * 2048 * 2);
  f16* dw1t_lo = (f16*)alloc(64ull * 2048 * 2);
  f16* dw2t_hi = (f16*)alloc(2048ull * 64 * 2);
  f16* dw2t_lo = (f16*)alloc(2048ull * 64 * 2);
  float* mixb = (float*)alloc(4096ull * 160 * 4);
  f16* wd1h = (f16*)alloc(4096ull * 64 * 2);
  f16* wd1l = (f16*)alloc(4096ull * 64 * 2);
  // arena -> total ~225.4 MB (< 229.6 proven-safe)
  char* R_A = alloc(4096ull * 2048 * 4);   // xxx hi/lo -> tdin hi/lo -> wbuf
  char* R_B = alloc(4096ull * 2048 * 4);   // rbuf / r~
  char* R_C = alloc(4096ull * 2048 * 4);   // kbuf
  char* R_D = alloc(4096ull * 2048 * 4);   // vbuf
  char* R_E = alloc(4096ull * 2048 * 2);   // W-stage -> obuf(f16) (in-place gnorm)
  char* F12 = alloc(4096ull * 2048 * 4);   // kx | vx  -> Ebuf + Dbuf
  char* F3 = alloc(4096ull * 2048 * 2);    // rx -> gbuf
  char* F4 = alloc(4096ull * 2048 * 2);    // gx -> wt_o

  f16* xh = (f16*)R_A;
  f16* xl = (f16*)(R_A + 4096ull * 2048 * 2);
  f16* th = (f16*)R_A;                      // tdin hi (xxx dead after mix1)
  f16* tl = (f16*)(R_A + 4096ull * 2048 * 2);
  float* wbuf = (float*)R_A;                // after wd1 consumed tdin
  float* rbuf = (float*)R_B;
  float* kbuf = (float*)R_C;
  float* vbuf = (float*)R_D;
  f16* wstage = (f16*)R_E;
  f16* obuf = (f16*)R_E;
  f16* kx = (f16*)F12;
  f16* vx = (f16*)(F12 + 4096ull * 2048 * 2);
  float* Ebuf = (float*)F12;                     // 256*7*4096*4 = 29.36 MB
  float* Dbuf = (float*)(F12 + 29360128);        // 256*8*64*4 = 0.52 MB
  f16* rx = (f16*)F3;
  f16* gbuf = (f16*)F3;
  f16* gx = (f16*)F4;
  f16* wt_o = (f16*)F4;

  dim3 tb(32, 8);
  // small split transposes
  k_transpose_split<<<dim3(5, 64), tb, 0, stream>>>(maa_w1, w1t_hi, w1t_lo, 2048, 160);
  k_tsplit_w2<<<dim3(64, 1, 5), tb, 0, stream>>>(maa_w2, w2t_hi, w2t_lo);
  k_transpose_split<<<dim3(2, 64), tb, 0, stream>>>(decay_w1, dw1t_hi, dw1t_lo, 2048, 64);
  k_transpose_split<<<dim3(64, 2), tb, 0, stream>>>(decay_w2, dw2t_hi, dw2t_lo, 64, 2048);

  // pre-scan chain
  k_xxx<<<8192, 256, 0, stream>>>(hs, shift_st, positions, maa_x, xh, xl);
  k_mix1_split<<<dim3(256, 10), 64, 0, stream>>>(xh, xl, w1t_hi, w1t_lo, mixb);
  k_tmp5_split<<<dim3(256, 128), 64, 0, stream>>>(mixb, w2t_hi, w2t_lo, hs, shift_st,
      positions, maa_w, maa_k, maa_v, maa_r, maa_g, th, tl, kx, vx, rx, gx);
  k_wd1_split<<<dim3(256, 4), 64, 0, stream>>>(th, tl, dw1t_hi, dw1t_lo, wd1h, wd1l);
  k_wdecay_split<<<dim3(256, 128), 64, 0, stream>>>(wd1h, wd1l, dw2t_hi, dw2t_lo,
                                                    time_decay, wbuf);

  // big projections (plain f16 MFMA, fp32 outputs for r/k/v)
  dim3 gg(2048 / GBN, 4096 / GBM);
  k_transpose_cast<<<dim3(64, 64), tb, 0, stream>>>(W_r, wstage, 2048, 2048);
  k_gemm_big<0><<<gg, 256, 0, stream>>>(rx, wstage, rbuf, nullptr, 2048);
  k_transpose_cast<<<dim3(64, 64), tb, 0, stream>>>(W_k, wstage, 2048, 2048);
  k_gemm_big<0><<<gg, 256, 0, stream>>>(kx, wstage, kbuf, nullptr, 2048);
  k_transpose_cast<<<dim3(64, 64), tb, 0, stream>>>(W_v, wstage, 2048, 2048);
  k_gemm_big<0><<<gg, 256, 0, stream>>>(vx, wstage, vbuf, nullptr, 2048);
  k_transpose_cast<<<dim3(64, 64), tb, 0, stream>>>(W_g, wstage, 2048, 2048);
  k_gemm_big<2><<<gg, 256, 0, stream>>>(gx, wstage, nullptr, gbuf, 2048);
  k_transpose_cast<<<dim3(64, 64), tb, 0, stream>>>(W_o, wt_o, 2048, 2048);  // gx dead

  // chunked scan (8 chunks of 64, 1 wave per chunk) + exact recombination
  k_scanD<<<2048, 64, 0, stream>>>(rbuf, kbuf, vbuf, wbuf, kvstate, positions, faaaa,
                                   obuf, rbuf, Ebuf, Dbuf);
  k_comb<<<256, 256, 0, stream>>>(Ebuf, Dbuf);
  k_fix<<<1792, 256, 0, stream>>>(rbuf, Ebuf, obuf);

  // groupnorm * silu(g) (in-place) then output projection
  k_gnorm<<<4096, 256, 0, stream>>>(obuf, gbuf, ln_w, ln_b, obuf);
  k_gemm_big<0><<<gg, 256, 0, stream>>>(obuf, wt_o, (float*)d_out, nullptr, 2048);
}